// Round 1
// baseline (2880.729 us; speedup 1.0000x reference)
//
#include <hip/hip_runtime.h>
#include <math.h>

#define NB    16
#define NPIX  4096    // 64*64
#define NPOOL 1024    // 32*32
#define CIN   512
#define CD    64      // C/8
#define CG    256     // C/2

// ---------------------------------------------------------------------------
// Kernel 1: projections theta = x@wt+bt (per pixel),
//           phi = maxpool2x2(x@wp)+bp, g = maxpool2x2(x@wg)+bg
// Block: 4 pooled groups (16 pixels) of one batch. 256 threads.
// ---------------------------------------------------------------------------
__global__ __launch_bounds__(256) void proj_kernel(
    const float* __restrict__ x,
    const float* __restrict__ wt, const float* __restrict__ bt,
    const float* __restrict__ wp, const float* __restrict__ bp,
    const float* __restrict__ wg, const float* __restrict__ bg,
    float* __restrict__ theta, float* __restrict__ phi, float* __restrict__ g)
{
    __shared__ float  xs[16 * CIN];       // 32 KB: 16 pixels x 512 ch
    __shared__ float  redP[4][4][64];     // 4 KB: [gi][pixel][ch]
    __shared__ float4 redG[4][4][64];     // 16 KB: [gi][pixel][ch4]

    const int t    = threadIdx.x;
    const int pg0  = blockIdx.x * 4;       // first pooled group
    const int b    = pg0 >> 10;
    const int gidx = pg0 & 1023;
    const int ph   = gidx >> 5;            // pooled row
    const int pw0  = gidx & 31;            // pooled col base (multiple of 4)

    // Load 16 pixels: rows {2ph, 2ph+1}, cols {2pw0 .. 2pw0+7}
    const float4* x4  = (const float4*)x;
    float4*       xs4 = (float4*)xs;
#pragma unroll
    for (int j = 0; j < 8; ++j) {
        int i4 = t + 256 * j;             // 2048 float4 total
        int pl = i4 >> 7;                 // local pixel 0..15 (dy*8+dx)
        int c4 = i4 & 127;
        int dy = pl >> 3, dxl = pl & 7;
        int gpix = (2 * ph + dy) * 64 + 2 * pw0 + dxl;
        xs4[i4] = x4[(size_t)(b * NPIX + gpix) * 128 + c4];
    }
    __syncthreads();

    const int lp  = t >> 6;               // wave id -> pixel slot within group
    const int chS = t & 63;               // theta/phi channel; g float4-group
    const int pl0 = (lp >> 1) * 8 + (lp & 1);   // pl(gi) = pl0 + 2*gi

    float  accT[4] = {0.f, 0.f, 0.f, 0.f};
    float  accP[4] = {0.f, 0.f, 0.f, 0.f};
    float4 accG[4];
#pragma unroll
    for (int gi = 0; gi < 4; ++gi) accG[gi] = make_float4(0.f, 0.f, 0.f, 0.f);

    const float4* wg4 = (const float4*)wg;
    for (int c = 0; c < CIN; ++c) {
        float  wtv = wt[c * 64 + chS];
        float  wpv = wp[c * 64 + chS];
        float4 wgv = wg4[c * 64 + chS];
#pragma unroll
        for (int gi = 0; gi < 4; ++gi) {
            float xv = xs[(pl0 + 2 * gi) * CIN + c];   // wave-uniform (broadcast)
            accT[gi]   = fmaf(xv, wtv,   accT[gi]);
            accP[gi]   = fmaf(xv, wpv,   accP[gi]);
            accG[gi].x = fmaf(xv, wgv.x, accG[gi].x);
            accG[gi].y = fmaf(xv, wgv.y, accG[gi].y);
            accG[gi].z = fmaf(xv, wgv.z, accG[gi].z);
            accG[gi].w = fmaf(xv, wgv.w, accG[gi].w);
        }
    }

    // theta: per-pixel store (no pooling)
#pragma unroll
    for (int gi = 0; gi < 4; ++gi) {
        int pix = (2 * ph + (lp >> 1)) * 64 + 2 * (pw0 + gi) + (lp & 1);
        theta[(size_t)(b * NPIX + pix) * CD + chS] = accT[gi] + bt[chS];
    }
#pragma unroll
    for (int gi = 0; gi < 4; ++gi) {
        redP[gi][lp][chS] = accP[gi];
        redG[gi][lp][chS] = accG[gi];
    }
    __syncthreads();
    {
        int gi = t >> 6, ch = t & 63;
        int pidx = b * NPOOL + ph * 32 + pw0 + gi;
        float m = fmaxf(fmaxf(redP[gi][0][ch], redP[gi][1][ch]),
                        fmaxf(redP[gi][2][ch], redP[gi][3][ch]));
        phi[(size_t)pidx * CD + ch] = m + bp[ch];

        float4 a0 = redG[gi][0][ch], a1 = redG[gi][1][ch];
        float4 a2 = redG[gi][2][ch], a3 = redG[gi][3][ch];
        float4 bgv = ((const float4*)bg)[ch];
        float4 mg;
        mg.x = fmaxf(fmaxf(a0.x, a1.x), fmaxf(a2.x, a3.x)) + bgv.x;
        mg.y = fmaxf(fmaxf(a0.y, a1.y), fmaxf(a2.y, a3.y)) + bgv.y;
        mg.z = fmaxf(fmaxf(a0.z, a1.z), fmaxf(a2.z, a3.z)) + bgv.z;
        mg.w = fmaxf(fmaxf(a0.w, a1.w), fmaxf(a2.w, a3.w)) + bgv.w;
        ((float4*)g)[(size_t)pidx * 64 + ch] = mg;
    }
}

// ---------------------------------------------------------------------------
// Kernel 2: attn = softmax(theta @ phi^T) ; attn_g = attn @ g
// Block: 8 queries of one batch, all 1024 keys. 256 threads.
// ---------------------------------------------------------------------------
#define QPB 8
__global__ __launch_bounds__(256) void attn_kernel(
    const float* __restrict__ theta, const float* __restrict__ phi,
    const float* __restrict__ g, float* __restrict__ attn_g)
{
    __shared__ float th[QPB * CD];        // 2 KB
    __shared__ float at[NPOOL * QPB];     // 32 KB, layout [k][q]

    const int t  = threadIdx.x;
    const int b  = blockIdx.x >> 9;           // 512 q-tiles per batch
    const int q0 = (blockIdx.x & 511) * QPB;

    for (int i = t; i < QPB * CD; i += 256)
        th[i] = theta[(size_t)(b * NPIX + q0 + (i >> 6)) * CD + (i & 63)];
    __syncthreads();

    // --- logits: thread (q = t>>5, sub = t&31) handles k = kk*32+sub ---
    const int q = t >> 5, sub = t & 31;
    const float*  phb = phi + (size_t)b * NPOOL * CD;
    const float4* tr  = (const float4*)(th + q * CD);
    float lg[32];
    float mx = -1e30f;
#pragma unroll 4
    for (int kk = 0; kk < 32; ++kk) {
        int k = kk * 32 + sub;
        const float4* pr = (const float4*)(phb + (size_t)k * CD);
        float acc = 0.f;
#pragma unroll
        for (int c4 = 0; c4 < 16; ++c4) {
            float4 a = tr[c4], p = pr[c4];
            acc = fmaf(a.x, p.x, acc);
            acc = fmaf(a.y, p.y, acc);
            acc = fmaf(a.z, p.z, acc);
            acc = fmaf(a.w, p.w, acc);
        }
        lg[kk] = acc;
        mx = fmaxf(mx, acc);
    }
#pragma unroll
    for (int m = 1; m < 32; m <<= 1) mx = fmaxf(mx, __shfl_xor(mx, m));
    float sum = 0.f;
#pragma unroll
    for (int kk = 0; kk < 32; ++kk) { lg[kk] = __expf(lg[kk] - mx); sum += lg[kk]; }
#pragma unroll
    for (int m = 1; m < 32; m <<= 1) sum += __shfl_xor(sum, m);
    float inv = 1.0f / sum;
#pragma unroll
    for (int kk = 0; kk < 32; ++kk) at[(kk * 32 + sub) * QPB + q] = lg[kk] * inv;
    __syncthreads();

    // --- attn_g: thread owns channel d = t for all 8 queries ---
    const float* gb = g + (size_t)b * NPOOL * CG;
    float acc[QPB] = {0.f, 0.f, 0.f, 0.f, 0.f, 0.f, 0.f, 0.f};
    for (int k = 0; k < NPOOL; ++k) {
        float gv = gb[(size_t)k * CG + t];
        const float4* ar = (const float4*)&at[k * QPB];
        float4 a0 = ar[0], a1 = ar[1];
        acc[0] = fmaf(a0.x, gv, acc[0]);
        acc[1] = fmaf(a0.y, gv, acc[1]);
        acc[2] = fmaf(a0.z, gv, acc[2]);
        acc[3] = fmaf(a0.w, gv, acc[3]);
        acc[4] = fmaf(a1.x, gv, acc[4]);
        acc[5] = fmaf(a1.y, gv, acc[5]);
        acc[6] = fmaf(a1.z, gv, acc[6]);
        acc[7] = fmaf(a1.w, gv, acc[7]);
    }
#pragma unroll
    for (int q2 = 0; q2 < QPB; ++q2)
        attn_g[(size_t)(b * NPIX + q0 + q2) * CG + t] = acc[q2];
}

// ---------------------------------------------------------------------------
// Kernel 3: out = x + sigma * (attn_g @ w_o + b_o)
// Block: 16 pixels. 256 threads, each owns output channels t and t+256.
// ---------------------------------------------------------------------------
__global__ __launch_bounds__(256) void out_kernel(
    const float* __restrict__ x, const float* __restrict__ attn_g,
    const float* __restrict__ wo, const float* __restrict__ bo,
    const float* __restrict__ sigma, float* __restrict__ out)
{
    __shared__ float agt[CG * 16];        // 16 KB, layout [d][pixel]

    const int t  = threadIdx.x;
    const int b  = blockIdx.x >> 8;
    const int p0 = (blockIdx.x & 255) * 16;

#pragma unroll
    for (int j = 0; j < 16; ++j)
        agt[t * 16 + j] = attn_g[(size_t)(b * NPIX + p0 + j) * CG + t];
    __syncthreads();

    float acc0[16], acc1[16];
#pragma unroll
    for (int j = 0; j < 16; ++j) { acc0[j] = 0.f; acc1[j] = 0.f; }

    for (int d = 0; d < CG; ++d) {
        float w0 = wo[(size_t)d * CIN + t];
        float w1 = wo[(size_t)d * CIN + 256 + t];
        const float4* ar = (const float4*)&agt[d * 16];
        float av[16];
        *(float4*)&av[0]  = ar[0];
        *(float4*)&av[4]  = ar[1];
        *(float4*)&av[8]  = ar[2];
        *(float4*)&av[12] = ar[3];
#pragma unroll
        for (int j = 0; j < 16; ++j) {
            acc0[j] = fmaf(av[j], w0, acc0[j]);
            acc1[j] = fmaf(av[j], w1, acc1[j]);
        }
    }

    const float s = sigma[0];
    const float b0 = bo[t], b1 = bo[t + 256];
#pragma unroll
    for (int j = 0; j < 16; ++j) {
        size_t base = (size_t)(b * NPIX + p0 + j) * CIN;
        out[base + t]       = x[base + t]       + s * (acc0[j] + b0);
        out[base + t + 256] = x[base + t + 256] + s * (acc1[j] + b1);
    }
}

// ---------------------------------------------------------------------------
extern "C" void kernel_launch(void* const* d_in, const int* in_sizes, int n_in,
                              void* d_out, int out_size, void* d_ws, size_t ws_size,
                              hipStream_t stream)
{
    const float* x     = (const float*)d_in[0];
    const float* wt    = (const float*)d_in[1];
    const float* bt    = (const float*)d_in[2];
    const float* wp    = (const float*)d_in[3];
    const float* bp    = (const float*)d_in[4];
    const float* wg    = (const float*)d_in[5];
    const float* bg    = (const float*)d_in[6];
    const float* wo    = (const float*)d_in[7];
    const float* bo    = (const float*)d_in[8];
    const float* sigma = (const float*)d_in[9];
    float* out = (float*)d_out;

    // workspace layout (fp32): theta 16MB | phi 4MB | g 16MB | attn_g 64MB
    float* ws     = (float*)d_ws;
    float* theta  = ws;
    float* phi    = theta + (size_t)NB * NPIX * CD;
    float* g      = phi   + (size_t)NB * NPOOL * CD;
    float* attn_g = g     + (size_t)NB * NPOOL * CG;

    proj_kernel<<<NB * NPOOL / 4, 256, 0, stream>>>(x, wt, bt, wp, bp, wg, bg,
                                                    theta, phi, g);
    attn_kernel<<<NB * NPIX / QPB, 256, 0, stream>>>(theta, phi, g, attn_g);
    out_kernel<<<NB * NPIX / 16, 256, 0, stream>>>(x, attn_g, wo, bo, sigma, out);
}

// Round 2
// 1002.080 us; speedup vs baseline: 2.8747x; 2.8747x over previous
//
#include <hip/hip_runtime.h>
#include <math.h>

#define NB    16
#define NPIX  4096    // 64*64
#define NPOOL 1024    // 32*32
#define CIN   512
#define CD    64      // C/8
#define CG    256     // C/2

typedef unsigned short u16;
typedef unsigned int   u32;
typedef __attribute__((ext_vector_type(8)))  u16    u16x8;
typedef __attribute__((ext_vector_type(8)))  __bf16 bf16x8;
typedef __attribute__((ext_vector_type(16))) float  f32x16;

__device__ __forceinline__ u16 f2bf(float x) {
    u32 u = __builtin_bit_cast(u32, x);
    u += 0x7fffu + ((u >> 16) & 1u);          // round-to-nearest-even
    return (u16)(u >> 16);
}
__device__ __forceinline__ float bf2f(u16 h) {
    u32 u = ((u32)h) << 16;
    return __builtin_bit_cast(float, u);
}
__device__ __forceinline__ f32x16 mfma32(u16x8 a, u16x8 b, f32x16 c) {
    return __builtin_amdgcn_mfma_f32_32x32x16_bf16(
        __builtin_bit_cast(bf16x8, a), __builtin_bit_cast(bf16x8, b), c, 0, 0, 0);
}

// ---------------------------------------------------------------------------
// Kernel 1: projections -> bf16.  theta = x@wt+bt (per pixel),
// phi = maxpool2x2(x@wp)+bp, g = maxpool2x2(x@wg)+bg   (bias commutes w/ max)
// Block: 4 pooled groups (16 pixels) of one batch. 256 threads.
// ---------------------------------------------------------------------------
__global__ __launch_bounds__(256) void proj_kernel(
    const float* __restrict__ x,
    const float* __restrict__ wt, const float* __restrict__ bt,
    const float* __restrict__ wp, const float* __restrict__ bp,
    const float* __restrict__ wg, const float* __restrict__ bg,
    u16* __restrict__ theta, u16* __restrict__ phi, u16* __restrict__ g)
{
    __shared__ float  xs[16 * CIN];       // 32 KB
    __shared__ float  redP[4][4][64];
    __shared__ float4 redG[4][4][64];

    const int t    = threadIdx.x;
    const int pg0  = blockIdx.x * 4;
    const int b    = pg0 >> 10;
    const int gidx = pg0 & 1023;
    const int ph   = gidx >> 5;
    const int pw0  = gidx & 31;

    const float4* x4  = (const float4*)x;
    float4*       xs4 = (float4*)xs;
#pragma unroll
    for (int j = 0; j < 8; ++j) {
        int i4 = t + 256 * j;
        int pl = i4 >> 7;
        int c4 = i4 & 127;
        int dy = pl >> 3, dxl = pl & 7;
        int gpix = (2 * ph + dy) * 64 + 2 * pw0 + dxl;
        xs4[i4] = x4[(size_t)(b * NPIX + gpix) * 128 + c4];
    }
    __syncthreads();

    const int lp  = t >> 6;
    const int chS = t & 63;
    const int pl0 = (lp >> 1) * 8 + (lp & 1);

    float  accT[4] = {0.f, 0.f, 0.f, 0.f};
    float  accP[4] = {0.f, 0.f, 0.f, 0.f};
    float4 accG[4];
#pragma unroll
    for (int gi = 0; gi < 4; ++gi) accG[gi] = make_float4(0.f, 0.f, 0.f, 0.f);

    const float4* wg4 = (const float4*)wg;
    for (int c = 0; c < CIN; ++c) {
        float  wtv = wt[c * 64 + chS];
        float  wpv = wp[c * 64 + chS];
        float4 wgv = wg4[c * 64 + chS];
#pragma unroll
        for (int gi = 0; gi < 4; ++gi) {
            float xv = xs[(pl0 + 2 * gi) * CIN + c];
            accT[gi]   = fmaf(xv, wtv,   accT[gi]);
            accP[gi]   = fmaf(xv, wpv,   accP[gi]);
            accG[gi].x = fmaf(xv, wgv.x, accG[gi].x);
            accG[gi].y = fmaf(xv, wgv.y, accG[gi].y);
            accG[gi].z = fmaf(xv, wgv.z, accG[gi].z);
            accG[gi].w = fmaf(xv, wgv.w, accG[gi].w);
        }
    }

#pragma unroll
    for (int gi = 0; gi < 4; ++gi) {
        int pix = (2 * ph + (lp >> 1)) * 64 + 2 * (pw0 + gi) + (lp & 1);
        theta[(size_t)(b * NPIX + pix) * CD + chS] = f2bf(accT[gi] + bt[chS]);
    }
#pragma unroll
    for (int gi = 0; gi < 4; ++gi) {
        redP[gi][lp][chS] = accP[gi];
        redG[gi][lp][chS] = accG[gi];
    }
    __syncthreads();
    {
        int gi = t >> 6, ch = t & 63;
        int pidx = b * NPOOL + ph * 32 + pw0 + gi;
        float m = fmaxf(fmaxf(redP[gi][0][ch], redP[gi][1][ch]),
                        fmaxf(redP[gi][2][ch], redP[gi][3][ch]));
        phi[(size_t)pidx * CD + ch] = f2bf(m + bp[ch]);

        float4 a0 = redG[gi][0][ch], a1 = redG[gi][1][ch];
        float4 a2 = redG[gi][2][ch], a3 = redG[gi][3][ch];
        float4 bgv = ((const float4*)bg)[ch];
        ushort4 mg;
        mg.x = f2bf(fmaxf(fmaxf(a0.x, a1.x), fmaxf(a2.x, a3.x)) + bgv.x);
        mg.y = f2bf(fmaxf(fmaxf(a0.y, a1.y), fmaxf(a2.y, a3.y)) + bgv.y);
        mg.z = f2bf(fmaxf(fmaxf(a0.z, a1.z), fmaxf(a2.z, a3.z)) + bgv.z);
        mg.w = f2bf(fmaxf(fmaxf(a0.w, a1.w), fmaxf(a2.w, a3.w)) + bgv.w);
        ((ushort4*)g)[(size_t)pidx * 64 + ch] = mg;
    }
}

// ---------------------------------------------------------------------------
// Kernel 1.5: transpose g [b][1024 k][256 d] -> gt [b][256 d][1024 k]  (bf16)
// 64x64 tiles, 256 threads, 1024 blocks.
// ---------------------------------------------------------------------------
__global__ __launch_bounds__(256) void transpose_g_kernel(
    const u16* __restrict__ g, u16* __restrict__ gt)
{
    __shared__ u16 tile[64][66];
    const int t  = threadIdx.x;
    const int blk = blockIdx.x;           // b*64 + kt*4 + dt
    const int b  = blk >> 6;
    const int kt = (blk >> 2) & 15;
    const int dt = blk & 3;
    const int col2 = t & 31, r0 = t >> 5;

    const u16* gb = g + (size_t)b * NPOOL * CG + (size_t)kt * 64 * CG + dt * 64;
#pragma unroll
    for (int j = 0; j < 8; ++j) {
        int k = r0 + 8 * j;
        ushort2 v = *(const ushort2*)(gb + (size_t)k * CG + col2 * 2);
        tile[k][col2 * 2]     = v.x;
        tile[k][col2 * 2 + 1] = v.y;
    }
    __syncthreads();
    u16* gtb = gt + (size_t)b * CG * NPOOL + (size_t)dt * 64 * NPOOL + kt * 64;
#pragma unroll
    for (int j = 0; j < 8; ++j) {
        int d = r0 + 8 * j;
        ushort2 v;
        v.x = tile[col2 * 2][d];
        v.y = tile[col2 * 2 + 1][d];
        *(ushort2*)(gtb + (size_t)d * NPOOL + col2 * 2) = v;
    }
}

// ---------------------------------------------------------------------------
// Kernel 2: MFMA attention.  Block = 32 queries x 1024 keys, 256 thr (4 waves).
// Phase 1: S = theta @ phi^T (bf16 MFMA) -> LDS (bf16, stride-padded)
// Phase 2: rowwise softmax (unnormalized exp stored, inv-sum kept)
// Phase 3: O = P @ g via gt, normalized in epilogue -> attn_g fp32
// ---------------------------------------------------------------------------
#define SLD 1032   // S row stride in bf16 elems (516 dwords == 4 mod 32: balanced)
__global__ __launch_bounds__(256) void attn_mfma_kernel(
    const u16* __restrict__ theta, const u16* __restrict__ phi,
    const u16* __restrict__ gt, float* __restrict__ attn_g)
{
    __shared__ u16   S[32 * SLD];         // 66 KB
    __shared__ float rinv[32];

    const int t  = threadIdx.x;
    const int w  = t >> 6;                // wave 0..3
    const int l  = t & 63;
    const int lr = l & 31;                // row/col within 32-tile
    const int lh = l >> 5;                // half-wave -> k-offset 8*lh
    const int b  = blockIdx.x >> 7;       // 128 q-tiles per batch
    const int q0 = (blockIdx.x & 127) * 32;

    // ---- Phase 1: S = theta @ phi^T ----
    const u16* thb = theta + ((size_t)(b * NPIX + q0 + lr)) * CD + lh * 8;
    u16x8 afr[4];
#pragma unroll
    for (int ki = 0; ki < 4; ++ki)
        afr[ki] = *(const u16x8*)(thb + ki * 16);

    const u16* phb = phi + (size_t)b * NPOOL * CD;
#pragma unroll 2
    for (int nt = 0; nt < 8; ++nt) {
        int k0 = w * 256 + nt * 32;
        const u16* pb = phb + (size_t)(k0 + lr) * CD + lh * 8;
        f32x16 acc = {};
#pragma unroll
        for (int ki = 0; ki < 4; ++ki)
            acc = mfma32(afr[ki], *(const u16x8*)(pb + ki * 16), acc);
        // D layout: col = lr, row = (r&3) + 8*(r>>2) + 4*lh
#pragma unroll
        for (int r = 0; r < 16; ++r) {
            int row = (r & 3) + 8 * (r >> 2) + 4 * lh;
            S[row * SLD + k0 + lr] = f2bf(acc[r]);
        }
    }
    __syncthreads();

    // ---- Phase 2: softmax over each of 32 rows (8 threads/row) ----
    {
        const int row = t >> 3, cg = t & 7;
        u16* srow = S + row * SLD;
        float mx = -1e30f;
#pragma unroll
        for (int i = 0; i < 16; ++i) {
            u16x8 v = *(const u16x8*)(srow + cg * 8 + 64 * i);
#pragma unroll
            for (int j = 0; j < 8; ++j) mx = fmaxf(mx, bf2f(v[j]));
        }
        mx = fmaxf(mx, __shfl_xor(mx, 1));
        mx = fmaxf(mx, __shfl_xor(mx, 2));
        mx = fmaxf(mx, __shfl_xor(mx, 4));
        float sum = 0.f;
#pragma unroll
        for (int i = 0; i < 16; ++i) {
            u16* p = srow + cg * 8 + 64 * i;
            u16x8 v = *(const u16x8*)p;
            u16x8 e;
#pragma unroll
            for (int j = 0; j < 8; ++j) {
                float ev = __expf(bf2f(v[j]) - mx);
                sum += ev;
                e[j] = f2bf(ev);
            }
            *(u16x8*)p = e;
        }
        sum += __shfl_xor(sum, 1);
        sum += __shfl_xor(sum, 2);
        sum += __shfl_xor(sum, 4);
        if (cg == 0) rinv[row] = 1.0f / sum;
    }
    __syncthreads();

    // ---- Phase 3: O = P @ g  (wave w owns output cols [64w, 64w+64)) ----
    const u16* gtb = gt + (size_t)b * CG * NPOOL;
    const u16* gp0 = gtb + (size_t)(w * 64 + lr) * NPOOL + lh * 8;
    const u16* gp1 = gp0 + (size_t)32 * NPOOL;
    const u16* arow = S + lr * SLD + lh * 8;
    f32x16 o0 = {}, o1 = {};
#pragma unroll 4
    for (int k0 = 0; k0 < NPOOL; k0 += 16) {
        u16x8 a  = *(const u16x8*)(arow + k0);
        u16x8 b0 = *(const u16x8*)(gp0 + k0);
        u16x8 b1 = *(const u16x8*)(gp1 + k0);
        o0 = mfma32(a, b0, o0);
        o1 = mfma32(a, b1, o1);
    }

    float* ob = attn_g + ((size_t)(b * NPIX + q0)) * CG;
#pragma unroll
    for (int r = 0; r < 16; ++r) {
        int qrow = (r & 3) + 8 * (r >> 2) + 4 * lh;
        float inv = rinv[qrow];
        ob[(size_t)qrow * CG + w * 64 + lr]      = o0[r] * inv;
        ob[(size_t)qrow * CG + w * 64 + 32 + lr] = o1[r] * inv;
    }
}

// ---------------------------------------------------------------------------
// Kernel 3: out = x + sigma * (attn_g @ w_o + b_o)    (unchanged fp32)
// ---------------------------------------------------------------------------
__global__ __launch_bounds__(256) void out_kernel(
    const float* __restrict__ x, const float* __restrict__ attn_g,
    const float* __restrict__ wo, const float* __restrict__ bo,
    const float* __restrict__ sigma, float* __restrict__ out)
{
    __shared__ float agt[CG * 16];

    const int t  = threadIdx.x;
    const int b  = blockIdx.x >> 8;
    const int p0 = (blockIdx.x & 255) * 16;

#pragma unroll
    for (int j = 0; j < 16; ++j)
        agt[t * 16 + j] = attn_g[(size_t)(b * NPIX + p0 + j) * CG + t];
    __syncthreads();

    float acc0[16], acc1[16];
#pragma unroll
    for (int j = 0; j < 16; ++j) { acc0[j] = 0.f; acc1[j] = 0.f; }

    for (int d = 0; d < CG; ++d) {
        float w0 = wo[(size_t)d * CIN + t];
        float w1 = wo[(size_t)d * CIN + 256 + t];
        const float4* ar = (const float4*)&agt[d * 16];
        float av[16];
        *(float4*)&av[0]  = ar[0];
        *(float4*)&av[4]  = ar[1];
        *(float4*)&av[8]  = ar[2];
        *(float4*)&av[12] = ar[3];
#pragma unroll
        for (int j = 0; j < 16; ++j) {
            acc0[j] = fmaf(av[j], w0, acc0[j]);
            acc1[j] = fmaf(av[j], w1, acc1[j]);
        }
    }

    const float s = sigma[0];
    const float b0 = bo[t], b1 = bo[t + 256];
#pragma unroll
    for (int j = 0; j < 16; ++j) {
        size_t base = (size_t)(b * NPIX + p0 + j) * CIN;
        out[base + t]       = x[base + t]       + s * (acc0[j] + b0);
        out[base + t + 256] = x[base + t + 256] + s * (acc1[j] + b1);
    }
}

// ---------------------------------------------------------------------------
extern "C" void kernel_launch(void* const* d_in, const int* in_sizes, int n_in,
                              void* d_out, int out_size, void* d_ws, size_t ws_size,
                              hipStream_t stream)
{
    const float* x     = (const float*)d_in[0];
    const float* wt    = (const float*)d_in[1];
    const float* bt    = (const float*)d_in[2];
    const float* wp    = (const float*)d_in[3];
    const float* bp    = (const float*)d_in[4];
    const float* wg    = (const float*)d_in[5];
    const float* bg    = (const float*)d_in[6];
    const float* wo    = (const float*)d_in[7];
    const float* bo    = (const float*)d_in[8];
    const float* sigma = (const float*)d_in[9];
    float* out = (float*)d_out;

    // ws layout: theta bf16 8MB | phi bf16 2MB | g bf16 8MB | gt bf16 8MB |
    //            attn_g fp32 64MB                                  (= 90 MB)
    char* ws = (char*)d_ws;
    u16*   theta  = (u16*)(ws);
    u16*   phi    = (u16*)(ws + ((size_t)8  << 20));
    u16*   g      = (u16*)(ws + ((size_t)10 << 20));
    u16*   gt     = (u16*)(ws + ((size_t)18 << 20));
    float* attn_g = (float*)(ws + ((size_t)26 << 20));

    proj_kernel<<<NB * NPOOL / 4, 256, 0, stream>>>(x, wt, bt, wp, bp, wg, bg,
                                                    theta, phi, g);
    transpose_g_kernel<<<NB * 64, 256, 0, stream>>>(g, gt);
    attn_mfma_kernel<<<NB * NPIX / 32, 256, 0, stream>>>(theta, phi, gt, attn_g);
    out_kernel<<<NB * NPIX / 16, 256, 0, stream>>>(x, attn_g, wo, bo, sigma, out);
}

// Round 3
// 502.243 us; speedup vs baseline: 5.7357x; 1.9952x over previous
//
#include <hip/hip_runtime.h>
#include <math.h>

#define NB    16
#define NPIX  4096    // 64*64
#define NPOOL 1024    // 32*32
#define CIN   512
#define CD    64      // C/8
#define CG    256     // C/2

typedef unsigned short u16;
typedef unsigned int   u32;
typedef __attribute__((ext_vector_type(8)))  u16    u16x8;
typedef __attribute__((ext_vector_type(8)))  __bf16 bf16x8;
typedef __attribute__((ext_vector_type(16))) float  f32x16;

__device__ __forceinline__ u16 f2bf(float x) {
    u32 u = __builtin_bit_cast(u32, x);
    u += 0x7fffu + ((u >> 16) & 1u);          // round-to-nearest-even
    return (u16)(u >> 16);
}
__device__ __forceinline__ float bf2f(u16 h) {
    u32 u = ((u32)h) << 16;
    return __builtin_bit_cast(float, u);
}
__device__ __forceinline__ f32x16 mfma32(u16x8 a, u16x8 b, f32x16 c) {
    return __builtin_amdgcn_mfma_f32_32x32x16_bf16(
        __builtin_bit_cast(bf16x8, a), __builtin_bit_cast(bf16x8, b), c, 0, 0, 0);
}

// ---------------------------------------------------------------------------
// Kernel 0: prep — transpose weights to bf16 [n][k] layout + concat bias.
//   WT [384][512]  = [wt | wp | wg]^T     (n-major, k contiguous)
//   WOT[512][256]  = wo^T
//   biasP[384] fp32 = [bt | bp | bg]
// Blocks 0..319: one 32x32 transpose tile each.  Block 320: bias concat.
// ---------------------------------------------------------------------------
__global__ __launch_bounds__(256) void prep_kernel(
    const float* __restrict__ wt, const float* __restrict__ wp,
    const float* __restrict__ wg, const float* __restrict__ wo,
    const float* __restrict__ bt, const float* __restrict__ bp,
    const float* __restrict__ bg,
    u16* __restrict__ WT, u16* __restrict__ WOT, float* __restrict__ biasP)
{
    const int bx = blockIdx.x;
    const int t  = threadIdx.x;

    if (bx == 320) {
        for (int i = t; i < 384; i += 256)
            biasP[i] = (i < 64) ? bt[i] : (i < 128) ? bp[i - 64] : bg[i - 128];
        return;
    }

    const float* src; u16* dst; int N, K, kt, nt;
    if (bx < 32)       { src = wt; dst = WT;             N = 64;  K = 512; kt = bx >> 1;        nt = bx & 1; }
    else if (bx < 64)  { src = wp; dst = WT + 64 * 512;  N = 64;  K = 512; kt = (bx - 32) >> 1; nt = (bx - 32) & 1; }
    else if (bx < 192) { src = wg; dst = WT + 128 * 512; N = 256; K = 512; kt = (bx - 64) >> 3; nt = (bx - 64) & 7; }
    else               { src = wo; dst = WOT;            N = 512; K = 256; kt = (bx - 192) >> 4; nt = (bx - 192) & 15; }

    __shared__ float tile[32][33];
    {
        int r  = t >> 3;            // 0..31 source row (k)
        int c4 = (t & 7) * 4;       // 0..28 source col (n)
        float4 v = *(const float4*)(src + (size_t)(kt * 32 + r) * N + nt * 32 + c4);
        tile[r][c4]     = v.x;
        tile[r][c4 + 1] = v.y;
        tile[r][c4 + 2] = v.z;
        tile[r][c4 + 3] = v.w;
    }
    __syncthreads();
    {
        int n  = t >> 3;            // 0..31 dst row (n)
        int k4 = (t & 7) * 4;       // 0..28 dst col (k)
        ushort4 wv;
        wv.x = f2bf(tile[k4][n]);
        wv.y = f2bf(tile[k4 + 1][n]);
        wv.z = f2bf(tile[k4 + 2][n]);
        wv.w = f2bf(tile[k4 + 3][n]);
        *(ushort4*)(dst + (size_t)(nt * 32 + n) * K + kt * 32 + k4) = wv;
    }
}

// ---------------------------------------------------------------------------
// Kernel 1: proj GEMM (MFMA).  C[65536 x 384] = x(bf16-cast) @ WT^T.
// 128x128 tile, 4 waves each 64x64 (2x2 of 32x32x16 MFMA), BK=32.
// Epilogue: + bias, split cols into theta / phiF / gF (all bf16, per-pixel).
// ---------------------------------------------------------------------------
#define AST 40   // LDS row stride in bf16 (32 + 8 pad, 80B = 16B-aligned)
__global__ __launch_bounds__(256) void proj_gemm_kernel(
    const float* __restrict__ x, const u16* __restrict__ WT,
    const float* __restrict__ biasP,
    u16* __restrict__ theta, u16* __restrict__ phiF, u16* __restrict__ gF)
{
    __shared__ u16 As[128 * AST];   // 10 KB
    __shared__ u16 Bs[128 * AST];   // 10 KB

    const int t  = threadIdx.x;
    const int w  = t >> 6, l = t & 63, lr = l & 31, lh = l >> 5;
    const int mt = blockIdx.x / 3, nt = blockIdx.x % 3;
    const int m0 = mt * 128, n0 = nt * 128;
    const int mw = (w & 1) * 64, nw = (w >> 1) * 64;

    const int srow = t >> 1;             // staging row 0..127
    const int sks  = (t & 1) * 16;       // staging k offset

    f32x16 acc[2][2] = {};

    for (int k0 = 0; k0 < 512; k0 += 32) {
        // --- stage A: x fp32 -> bf16 ---
        {
            const float4* ap = (const float4*)(x + (size_t)(m0 + srow) * 512 + k0 + sks);
            float4 v0 = ap[0], v1 = ap[1], v2 = ap[2], v3 = ap[3];
            u16x8 a0, a1;
            a0[0] = f2bf(v0.x); a0[1] = f2bf(v0.y); a0[2] = f2bf(v0.z); a0[3] = f2bf(v0.w);
            a0[4] = f2bf(v1.x); a0[5] = f2bf(v1.y); a0[6] = f2bf(v1.z); a0[7] = f2bf(v1.w);
            a1[0] = f2bf(v2.x); a1[1] = f2bf(v2.y); a1[2] = f2bf(v2.z); a1[3] = f2bf(v2.w);
            a1[4] = f2bf(v3.x); a1[5] = f2bf(v3.y); a1[6] = f2bf(v3.z); a1[7] = f2bf(v3.w);
            *(u16x8*)&As[srow * AST + sks]     = a0;
            *(u16x8*)&As[srow * AST + sks + 8] = a1;
        }
        // --- stage B: WT bf16 ---
        {
            const u16x8* bp = (const u16x8*)(WT + (size_t)(n0 + srow) * 512 + k0 + sks);
            *(u16x8*)&Bs[srow * AST + sks]     = bp[0];
            *(u16x8*)&Bs[srow * AST + sks + 8] = bp[1];
        }
        __syncthreads();
#pragma unroll
        for (int ki = 0; ki < 2; ++ki) {
            u16x8 af0 = *(const u16x8*)&As[(mw + lr)      * AST + ki * 16 + lh * 8];
            u16x8 af1 = *(const u16x8*)&As[(mw + 32 + lr) * AST + ki * 16 + lh * 8];
            u16x8 bf0 = *(const u16x8*)&Bs[(nw + lr)      * AST + ki * 16 + lh * 8];
            u16x8 bf1 = *(const u16x8*)&Bs[(nw + 32 + lr) * AST + ki * 16 + lh * 8];
            acc[0][0] = mfma32(af0, bf0, acc[0][0]);
            acc[0][1] = mfma32(af0, bf1, acc[0][1]);
            acc[1][0] = mfma32(af1, bf0, acc[1][0]);
            acc[1][1] = mfma32(af1, bf1, acc[1][1]);
        }
        __syncthreads();
    }

    // --- epilogue: bias + column split (segment is wave-uniform per ni) ---
#pragma unroll
    for (int mi = 0; mi < 2; ++mi) {
#pragma unroll
        for (int ni = 0; ni < 2; ++ni) {
            const int nb = n0 + nw + ni * 32;       // segment base (uniform)
            const int n  = nb + lr;
            const float bv = biasP[n];
            u16* dst; int ld, col;
            if (nb < 64)        { dst = theta; ld = 64;  col = n; }
            else if (nb < 128)  { dst = phiF;  ld = 64;  col = n - 64; }
            else                { dst = gF;    ld = 256; col = n - 128; }
#pragma unroll
            for (int r = 0; r < 16; ++r) {
                int row = m0 + mw + mi * 32 + (r & 3) + 8 * (r >> 2) + 4 * lh;
                dst[(size_t)row * ld + col] = f2bf(acc[mi][ni][r] + bv);
            }
        }
    }
}

// ---------------------------------------------------------------------------
// Kernel 2: 2x2 max-pool of phiF/gF + transpose of g.
//   phi[b][1024][64]  = pool(phiF)          (k-major rows)
//   gt [b][256][1024] = pool(gF) transposed (d-major rows)
// Block = (b, pooled row ph). 512 blocks, 256 threads.
// ---------------------------------------------------------------------------
__global__ __launch_bounds__(256) void pool_kernel(
    const u16* __restrict__ phiF, const u16* __restrict__ gF,
    u16* __restrict__ phi, u16* __restrict__ gt)
{
    const int t  = threadIdx.x;
    const int b  = blockIdx.x >> 5;
    const int ph = blockIdx.x & 31;

    // --- phi: thread = (pw = t>>3, d-octet = t&7) ---
    {
        const int pw = t >> 3, dq = (t & 7) * 8;
        const u16* base = phiF + ((size_t)(b * NPIX + 2 * ph * 64 + 2 * pw)) * 64 + dq;
        u16x8 v00 = *(const u16x8*)(base);
        u16x8 v01 = *(const u16x8*)(base + 64);
        u16x8 v10 = *(const u16x8*)(base + 64 * 64);
        u16x8 v11 = *(const u16x8*)(base + 64 * 64 + 64);
        u16x8 m;
#pragma unroll
        for (int j = 0; j < 8; ++j) {
            float mf = fmaxf(fmaxf(bf2f(v00[j]), bf2f(v01[j])),
                             fmaxf(bf2f(v10[j]), bf2f(v11[j])));
            m[j] = f2bf(mf);
        }
        *(u16x8*)(phi + ((size_t)(b * NPOOL + ph * 32 + pw)) * 64 + dq) = m;
    }
    // --- gt: thread = channel d, loops 32 pool cols ---
    {
        const u16* gb = gF + ((size_t)(b * NPIX + 2 * ph * 64)) * 256 + t;
        u16 buf[32];
#pragma unroll
        for (int kp = 0; kp < 32; ++kp) {
            float m = fmaxf(
                fmaxf(bf2f(gb[(size_t)(2 * kp) * 256]),      bf2f(gb[(size_t)(2 * kp + 1) * 256])),
                fmaxf(bf2f(gb[(size_t)(64 + 2 * kp) * 256]), bf2f(gb[(size_t)(64 + 2 * kp + 1) * 256])));
            buf[kp] = f2bf(m);
        }
        u16* go = gt + ((size_t)(b * CG + t)) * NPOOL + ph * 32;
#pragma unroll
        for (int j = 0; j < 4; ++j)
            *(u16x8*)(go + j * 8) = *(const u16x8*)&buf[j * 8];
    }
}

// ---------------------------------------------------------------------------
// Kernel 3: MFMA attention (unchanged except bf16 attn_g output).
// ---------------------------------------------------------------------------
#define SLD 1032
__global__ __launch_bounds__(256) void attn_mfma_kernel(
    const u16* __restrict__ theta, const u16* __restrict__ phi,
    const u16* __restrict__ gt, u16* __restrict__ attn_g)
{
    __shared__ u16   S[32 * SLD];         // 66 KB
    __shared__ float rinv[32];

    const int t  = threadIdx.x;
    const int w  = t >> 6;
    const int l  = t & 63;
    const int lr = l & 31;
    const int lh = l >> 5;
    const int b  = blockIdx.x >> 7;
    const int q0 = (blockIdx.x & 127) * 32;

    // ---- Phase 1: S = theta @ phi^T ----
    const u16* thb = theta + ((size_t)(b * NPIX + q0 + lr)) * CD + lh * 8;
    u16x8 afr[4];
#pragma unroll
    for (int ki = 0; ki < 4; ++ki)
        afr[ki] = *(const u16x8*)(thb + ki * 16);

    const u16* phb = phi + (size_t)b * NPOOL * CD;
#pragma unroll 2
    for (int nt = 0; nt < 8; ++nt) {
        int k0 = w * 256 + nt * 32;
        const u16* pb = phb + (size_t)(k0 + lr) * CD + lh * 8;
        f32x16 acc = {};
#pragma unroll
        for (int ki = 0; ki < 4; ++ki)
            acc = mfma32(afr[ki], *(const u16x8*)(pb + ki * 16), acc);
#pragma unroll
        for (int r = 0; r < 16; ++r) {
            int row = (r & 3) + 8 * (r >> 2) + 4 * lh;
            S[row * SLD + k0 + lr] = f2bf(acc[r]);
        }
    }
    __syncthreads();

    // ---- Phase 2: rowwise softmax (8 threads per row) ----
    {
        const int row = t >> 3, cg = t & 7;
        u16* srow = S + row * SLD;
        float mx = -1e30f;
#pragma unroll
        for (int i = 0; i < 16; ++i) {
            u16x8 v = *(const u16x8*)(srow + cg * 8 + 64 * i);
#pragma unroll
            for (int j = 0; j < 8; ++j) mx = fmaxf(mx, bf2f(v[j]));
        }
        mx = fmaxf(mx, __shfl_xor(mx, 1));
        mx = fmaxf(mx, __shfl_xor(mx, 2));
        mx = fmaxf(mx, __shfl_xor(mx, 4));
        float sum = 0.f;
#pragma unroll
        for (int i = 0; i < 16; ++i) {
            u16* p = srow + cg * 8 + 64 * i;
            u16x8 v = *(const u16x8*)p;
            u16x8 e;
#pragma unroll
            for (int j = 0; j < 8; ++j) {
                float ev = __expf(bf2f(v[j]) - mx);
                sum += ev;
                e[j] = f2bf(ev);
            }
            *(u16x8*)p = e;
        }
        sum += __shfl_xor(sum, 1);
        sum += __shfl_xor(sum, 2);
        sum += __shfl_xor(sum, 4);
        if (cg == 0) rinv[row] = 1.0f / sum;
    }
    __syncthreads();

    // ---- Phase 3: O = P @ g ----
    const u16* gtb = gt + (size_t)b * CG * NPOOL;
    const u16* gp0 = gtb + (size_t)(w * 64 + lr) * NPOOL + lh * 8;
    const u16* gp1 = gp0 + (size_t)32 * NPOOL;
    const u16* arow = S + lr * SLD + lh * 8;
    f32x16 o0 = {}, o1 = {};
#pragma unroll 4
    for (int k0 = 0; k0 < NPOOL; k0 += 16) {
        u16x8 a  = *(const u16x8*)(arow + k0);
        u16x8 b0 = *(const u16x8*)(gp0 + k0);
        u16x8 b1 = *(const u16x8*)(gp1 + k0);
        o0 = mfma32(a, b0, o0);
        o1 = mfma32(a, b1, o1);
    }

    u16* ob = attn_g + ((size_t)(b * NPIX + q0)) * CG;
#pragma unroll
    for (int r = 0; r < 16; ++r) {
        int qrow = (r & 3) + 8 * (r >> 2) + 4 * lh;
        float inv = rinv[qrow];
        ob[(size_t)qrow * CG + w * 64 + lr]      = f2bf(o0[r] * inv);
        ob[(size_t)qrow * CG + w * 64 + 32 + lr] = f2bf(o1[r] * inv);
    }
}

// ---------------------------------------------------------------------------
// Kernel 4: out GEMM (MFMA).  out = x + sigma*(attn_g @ wo + bo).
// C[65536 x 512] = attn_gB[65536 x 256] @ WOT^T.  Same tile structure.
// ---------------------------------------------------------------------------
__global__ __launch_bounds__(256) void out_gemm_kernel(
    const u16* __restrict__ attn_gB, const u16* __restrict__ WOT,
    const float* __restrict__ x, const float* __restrict__ bo,
    const float* __restrict__ sigma, float* __restrict__ out)
{
    __shared__ u16 As[128 * AST];
    __shared__ u16 Bs[128 * AST];

    const int t  = threadIdx.x;
    const int w  = t >> 6, l = t & 63, lr = l & 31, lh = l >> 5;
    const int mt = blockIdx.x >> 2, nt = blockIdx.x & 3;
    const int m0 = mt * 128, n0 = nt * 128;
    const int mw = (w & 1) * 64, nw = (w >> 1) * 64;

    const int srow = t >> 1;
    const int sks  = (t & 1) * 16;

    f32x16 acc[2][2] = {};

    for (int k0 = 0; k0 < 256; k0 += 32) {
        {
            const u16x8* ap = (const u16x8*)(attn_gB + (size_t)(m0 + srow) * 256 + k0 + sks);
            *(u16x8*)&As[srow * AST + sks]     = ap[0];
            *(u16x8*)&As[srow * AST + sks + 8] = ap[1];
        }
        {
            const u16x8* bp = (const u16x8*)(WOT + (size_t)(n0 + srow) * 256 + k0 + sks);
            *(u16x8*)&Bs[srow * AST + sks]     = bp[0];
            *(u16x8*)&Bs[srow * AST + sks + 8] = bp[1];
        }
        __syncthreads();
#pragma unroll
        for (int ki = 0; ki < 2; ++ki) {
            u16x8 af0 = *(const u16x8*)&As[(mw + lr)      * AST + ki * 16 + lh * 8];
            u16x8 af1 = *(const u16x8*)&As[(mw + 32 + lr) * AST + ki * 16 + lh * 8];
            u16x8 bf0 = *(const u16x8*)&Bs[(nw + lr)      * AST + ki * 16 + lh * 8];
            u16x8 bf1 = *(const u16x8*)&Bs[(nw + 32 + lr) * AST + ki * 16 + lh * 8];
            acc[0][0] = mfma32(af0, bf0, acc[0][0]);
            acc[0][1] = mfma32(af0, bf1, acc[0][1]);
            acc[1][0] = mfma32(af1, bf0, acc[1][0]);
            acc[1][1] = mfma32(af1, bf1, acc[1][1]);
        }
        __syncthreads();
    }

    const float s = sigma[0];
#pragma unroll
    for (int mi = 0; mi < 2; ++mi) {
#pragma unroll
        for (int ni = 0; ni < 2; ++ni) {
            const int n  = n0 + nw + ni * 32 + lr;
            const float bv = bo[n];
#pragma unroll
            for (int r = 0; r < 16; ++r) {
                int row = m0 + mw + mi * 32 + (r & 3) + 8 * (r >> 2) + 4 * lh;
                size_t idx = (size_t)row * 512 + n;
                out[idx] = x[idx] + s * (acc[mi][ni][r] + bv);
            }
        }
    }
}

// ---------------------------------------------------------------------------
extern "C" void kernel_launch(void* const* d_in, const int* in_sizes, int n_in,
                              void* d_out, int out_size, void* d_ws, size_t ws_size,
                              hipStream_t stream)
{
    const float* x     = (const float*)d_in[0];
    const float* wt    = (const float*)d_in[1];
    const float* bt    = (const float*)d_in[2];
    const float* wp    = (const float*)d_in[3];
    const float* bp    = (const float*)d_in[4];
    const float* wg    = (const float*)d_in[5];
    const float* bg    = (const float*)d_in[6];
    const float* wo    = (const float*)d_in[7];
    const float* bo    = (const float*)d_in[8];
    const float* sigma = (const float*)d_in[9];
    float* out = (float*)d_out;

    // ws layout (all bf16 unless noted):
    //  theta   [65536][64]   0 ..  8M
    //  phi     [16][1024][64]   8 .. 10M
    //  phiF    [65536][64]  10 .. 18M   (dead after pool)
    //  gF      [65536][256] 18 .. 50M   (dead after pool)
    //  attn_gB [65536][256] 10 .. 42M   (aliases phiF/gF; written after pool)
    //  gt      [16][256][1024] 50 .. 58M
    //  WT      [384][512]   58M
    //  WOT     [512][256]   58M + 384K
    //  biasP   [384] fp32   58M + 640K
    char* ws = (char*)d_ws;
    u16*   theta   = (u16*)(ws);
    u16*   phi     = (u16*)(ws + ((size_t)8  << 20));
    u16*   phiF    = (u16*)(ws + ((size_t)10 << 20));
    u16*   gF      = (u16*)(ws + ((size_t)18 << 20));
    u16*   attn_gB = (u16*)(ws + ((size_t)10 << 20));
    u16*   gt      = (u16*)(ws + ((size_t)50 << 20));
    u16*   WT      = (u16*)(ws + ((size_t)58 << 20));
    u16*   WOT     = (u16*)(ws + ((size_t)58 << 20) + (384 << 10));
    float* biasP   = (float*)(ws + ((size_t)58 << 20) + (640 << 10));

    prep_kernel<<<321, 256, 0, stream>>>(wt, wp, wg, wo, bt, bp, bg, WT, WOT, biasP);
    proj_gemm_kernel<<<512 * 3, 256, 0, stream>>>(x, WT, biasP, theta, phiF, gF);
    pool_kernel<<<NB * 32, 256, 0, stream>>>(phiF, gF, phi, gt);
    attn_mfma_kernel<<<NB * NPIX / 32, 256, 0, stream>>>(theta, phi, gt, attn_gB);
    out_gemm_kernel<<<512 * 4, 256, 0, stream>>>(attn_gB, WOT, x, bo, sigma, out);
}